// Round 12
// baseline (127.613 us; speedup 1.0000x reference)
//
#include <hip/hip_runtime.h>
#include <math.h>

#define EPS 1e-8f
typedef float f32x4 __attribute__((ext_vector_type(4)));

__device__ __forceinline__ float wredsum(float v) {
#pragma unroll
  for (int o = 32; o > 0; o >>= 1) v += __shfl_down(v, o, 64);
  return v;  // valid in lane 0
}

// 8 consecutive k-steps of a 4-col FMA: c += x[k] * w[k][0..3]
__device__ __forceinline__ void fma8(const float4* w, const float4 a,
                                     const float4 b, float4& c) {
  const float xs[8] = {a.x, a.y, a.z, a.w, b.x, b.y, b.z, b.w};
#pragma unroll
  for (int i = 0; i < 8; ++i) {
    c.x = fmaf(xs[i], w[i].x, c.x);
    c.y = fmaf(xs[i], w[i].y, c.y);
    c.z = fmaf(xs[i], w[i].z, c.z);
    c.w = fmaf(xs[i], w[i].w, c.w);
  }
}

// ---------------- Layer 1: EXACT R4 block (bit-exact p1) ---------------------
__global__ __launch_bounds__(256, 2) void k_l1(const float* __restrict__ xn,
                                               const float* __restrict__ xe,
                                               const float* __restrict__ W1,
                                               float* __restrict__ p1) {
  __shared__ float red[11 * 32 * 36];  // 50688 B
  const int cg  = threadIdx.x & 7;
  const int ks  = threadIdx.x >> 3;
  const int col = blockIdx.x * 32 + cg * 4;
  const int k0  = blockIdx.y * 256 + ks * 8;

  float4 w[8];
#pragma unroll
  for (int i = 0; i < 8; ++i)
    w[i] = *(const float4*)&W1[(size_t)(k0 + i) * 512 + col];

  float4 acc[11];
#pragma unroll
  for (int r = 0; r < 11; ++r) acc[r] = make_float4(0.f, 0.f, 0.f, 0.f);
  {
    const float4 a = *(const float4*)&xn[k0];
    const float4 b = *(const float4*)&xn[k0 + 4];
    fma8(w, a, b, acc[0]);
  }
#pragma unroll
  for (int r = 0; r < 10; ++r) {
    const float4 a = *(const float4*)&xe[r * 8192 + k0];
    const float4 b = *(const float4*)&xe[r * 8192 + k0 + 4];
    fma8(w, a, b, acc[r + 1]);
  }

#pragma unroll
  for (int r = 0; r < 11; ++r)
    *(float4*)&red[(r * 32 + ks) * 36 + cg * 4] = acc[r];
  __syncthreads();

  for (int o = threadIdx.x; o < 352; o += 256) {
    const int r = o >> 5, c = o & 31;
    float s = 0.f;
#pragma unroll
    for (int k = 0; k < 32; ++k) s += red[(r * 32 + k) * 36 + c];
    p1[((size_t)blockIdx.y * 11 + r) * 512 + blockIdx.x * 32 + c] = s;
  }
}

// ---------------- Tail: 33 blocks x 256, TWO levels, ONE hop -----------------
// Workers j<32: H1 cols [16j,16j+16) from p1 + W2 rows [16j..) coalesced ->
//   H2 partial for ALL 256 cols, atomicAdd into H2acc (memset-zeroed).
//   Side job: each dead-loads 4 KB of W3 (32 blocks = all 128 KB -> L3-warm).
//   Arrival: fetch_add(cnt).
// Finale (block 32): stages Wi1/Wi2 -> LDS at START (overlaps workers);
//   spins cnt==32 (the only hop); relu(H2acc+b2) -> enc via L3-warm W3;
//   similarity (wave0) || integrator (wave1).
__global__ __launch_bounds__(256) void k_tail(
    const float* __restrict__ p1, const float* __restrict__ b1,
    const float* __restrict__ W2, const float* __restrict__ b2,
    const float* __restrict__ W3, const float* __restrict__ b3,
    const float* __restrict__ mm,
    const float* __restrict__ Wi1, const float* __restrict__ bi1,
    const float* __restrict__ Wi2, const float* __restrict__ bi2,
    const float* __restrict__ Wi3, const float* __restrict__ bi3,
    float* __restrict__ H2acc, int* __restrict__ cnt,
    float* __restrict__ out) {
  __shared__ __align__(16) float smem[15104];  // 60416 B
  const int t = threadIdx.x;
  const int j = blockIdx.x;

  if (j < 32) {
    // ---- L3-warm W3 for the finale: 32 blocks x 256 threads = 8192 f4 ----
    float dead = ((const f32x4*)W3)[j * 256 + t][0];
    asm volatile("" ::"v"(dead));

    // ---- W2 rows [16j,16j+16), col t (16 KB/block, coalesced) ----
    float w2r[16];
#pragma unroll
    for (int i = 0; i < 16; ++i)
      w2r[i] = W2[(size_t)(j * 16 + i) * 256 + t];

    // ---- H1 cols [16j,16j+16) ----
    float* h1s = smem;  // [11][16]
    if (t < 176) {
      const int r = t >> 4, cc = t & 15;
      const int col = j * 16 + cc;
      float s = b1[col];
#pragma unroll
      for (int ch = 0; ch < 32; ++ch)
        s += p1[(size_t)(ch * 11 + r) * 512 + col];
      h1s[r * 16 + cc] = fmaxf(s, 0.f);
    }
    __syncthreads();

    // ---- H2 partial (col t, all rows) -> atomic accumulate ----
    float acc[11];
#pragma unroll
    for (int r = 0; r < 11; ++r) acc[r] = 0.f;
#pragma unroll
    for (int kk = 0; kk < 16; ++kk) {
#pragma unroll
      for (int r = 0; r < 11; ++r)
        acc[r] = fmaf(h1s[r * 16 + kk], w2r[kk], acc[r]);
    }
#pragma unroll
    for (int r = 0; r < 11; ++r) atomicAdd(&H2acc[r * 256 + t], acc[r]);

    __syncthreads();  // drain atomics (vmcnt at barrier)
    if (t == 0) {
      __threadfence();  // agent release
      __hip_atomic_fetch_add(cnt, 1, __ATOMIC_ACQ_REL,
                             __HIP_MEMORY_SCOPE_AGENT);
    }
    return;
  }

  // ======================== Finale (block 32) ===============================
  float* wi1s = smem;            // 8576
  float* wi2s = smem + 8576;     // 2048
  float* h2s  = smem + 10624;    // 2816
  float* encs = smem + 13440;    // 1408
  float* comb = smem + 14848;    // 134
  float* h1b  = smem + 14982;    // 64
  // Stage Wi1/Wi2 NOW — independent of workers; overlaps their whole phase.
  for (int i = t; i < 2144; i += 256)
    ((f32x4*)wi1s)[i] = ((const f32x4*)Wi1)[i];
  for (int i = t; i < 512; i += 256)
    ((f32x4*)wi2s)[i] = ((const f32x4*)Wi2)[i];

  if (t == 0) {  // the only cross-block hop
    while (__hip_atomic_load(cnt, __ATOMIC_RELAXED,
                             __HIP_MEMORY_SCOPE_AGENT) < 32)
      __builtin_amdgcn_s_sleep(2);
    __threadfence();  // acquire: all H2 atomic contributions visible
  }
  __syncthreads();

  // ---- H2 = relu(H2acc + b2) ----
  for (int o = t; o < 2816; o += 256)
    h2s[o] = fmaxf(H2acc[o] + b2[o & 255], 0.f);
  __syncthreads();

  // ---- enc = H2 @ W3 + b3 (W3 L3-warm; col t, k-outer, 11-row accs) ----
  if (t < 128) {
    float eacc[11];
#pragma unroll
    for (int r = 0; r < 11; ++r) eacc[r] = 0.f;
    for (int k = 0; k < 256; ++k) {
      const float w = W3[(size_t)k * 128 + t];
#pragma unroll
      for (int r = 0; r < 11; ++r)
        eacc[r] = fmaf(h2s[r * 256 + k], w, eacc[r]);
    }
    const float bb = b3[t];
#pragma unroll
    for (int r = 0; r < 11; ++r) encs[r * 128 + t] = eacc[r] + bb;
  }
  __syncthreads();

  // ---- similarity (wave 0) || integrator layer 1 (wave 1) ----
  float consist = 0.f;
  float n0 = 0.f, n1 = 0.f;
  if (t < 64) {
    n0 = encs[t]; n1 = encs[64 + t];
    comb[t] = n0; comb[64 + t] = n1;
    if (t < 6) comb[128 + t] = mm[t];
  }
  __syncthreads();  // comb ready
  if (t < 64) {
    const float nn = wredsum(n0 * n0 + n1 * n1);
#pragma unroll
    for (int r = 1; r <= 10; ++r) {
      const float e0 = encs[r * 128 + t];
      const float e1 = encs[r * 128 + 64 + t];
      const float d0 = e0 - n0, d1 = e1 - n1;
      const float g  = wredsum(d0 * d0 + d1 * d1);
      const float qq = wredsum(e0 * e0 + e1 * e1);
      const float dd = wredsum(e0 * n0 + e1 * n1);
      if (t == 0) {
        const float geo = sqrtf(g);
        const float den = fmaxf(sqrtf(nn), EPS) * fmaxf(sqrtf(qq), EPS);
        consist += geo - dd / den;
      }
    }
  } else if (t < 128) {
    const int tt = t - 64;
    float hh = bi1[tt];
#pragma unroll 4
    for (int k = 0; k < 134; ++k) hh = fmaf(comb[k], wi1s[k * 64 + tt], hh);
    h1b[tt] = fmaxf(hh, 0.f);
  }
  __syncthreads();
  if (t < 64) {
    float part = 0.f;
    if (t < 32) {
      float hh = bi2[t];
#pragma unroll 8
      for (int k = 0; k < 64; ++k) hh = fmaf(h1b[k], wi2s[k * 32 + t], hh);
      part = fmaxf(hh, 0.f) * Wi3[t];
    }
    const float qual = wredsum(part);
    if (t == 0) out[0] = consist * 0.1f + expf(-(qual + bi3[0]));
  }
}

extern "C" void kernel_launch(void* const* d_in, const int* in_sizes, int n_in,
                              void* d_out, int out_size, void* d_ws, size_t ws_size,
                              hipStream_t stream) {
  (void)in_sizes; (void)n_in; (void)out_size; (void)ws_size;
  const float* xn  = (const float*)d_in[0];
  const float* xe  = (const float*)d_in[1];
  const float* mm  = (const float*)d_in[2];
  const float* W1  = (const float*)d_in[3];
  const float* b1  = (const float*)d_in[4];
  const float* W2  = (const float*)d_in[5];
  const float* b2  = (const float*)d_in[6];
  const float* W3  = (const float*)d_in[7];
  const float* b3  = (const float*)d_in[8];
  const float* Wi1 = (const float*)d_in[9];
  const float* bi1 = (const float*)d_in[10];
  const float* Wi2 = (const float*)d_in[11];
  const float* bi2 = (const float*)d_in[12];
  const float* Wi3 = (const float*)d_in[13];
  const float* bi3 = (const float*)d_in[14];
  float* out = (float*)d_out;

  char* ws = (char*)d_ws;
  float* p1    = (float*)(ws);            // 32*11*512*4 = 720896 B
  float* H2acc = (float*)(ws + 720896);   // 11*256*4    =  11264 B
  int*   cnt   = (int*)  (ws + 732160);   // 4 B

  // Zero the atomic accumulator + arrival counter (stream-ordered, graph-safe).
  hipMemsetAsync(ws + 720896, 0, 11268, stream);
  hipLaunchKernelGGL(k_l1,   dim3(16, 32), dim3(256), 0, stream,
                     xn, xe, W1, p1);
  hipLaunchKernelGGL(k_tail, dim3(33),     dim3(256), 0, stream,
                     p1, b1, W2, b2, W3, b3, mm,
                     Wi1, bi1, Wi2, bi2, Wi3, bi3, H2acc, cnt, out);
}

// Round 13
// 109.390 us; speedup vs baseline: 1.1666x; 1.1666x over previous
//
#include <hip/hip_runtime.h>
#include <math.h>

#define EPS 1e-8f
typedef float f32x4 __attribute__((ext_vector_type(4)));

__device__ __forceinline__ float wredsum(float v) {
#pragma unroll
  for (int o = 32; o > 0; o >>= 1) v += __shfl_down(v, o, 64);
  return v;  // valid in lane 0
}

// 8 consecutive k-steps of a 4-col FMA: c += x[k] * w[k][0..3]
__device__ __forceinline__ void fma8(const float4* w, const float4 a,
                                     const float4 b, float4& c) {
  const float xs[8] = {a.x, a.y, a.z, a.w, b.x, b.y, b.z, b.w};
#pragma unroll
  for (int i = 0; i < 8; ++i) {
    c.x = fmaf(xs[i], w[i].x, c.x);
    c.y = fmaf(xs[i], w[i].y, c.y);
    c.z = fmaf(xs[i], w[i].z, c.z);
    c.w = fmaf(xs[i], w[i].w, c.w);
  }
}

// ---------------- Layer 1: [11,8192] @ [8192,512] -> 32 k-chunk partials -----
// EXACT R4 structure (best measured); plus bars zero-init for the tail.
__global__ __launch_bounds__(256, 2) void k_l1(const float* __restrict__ xn,
                                               const float* __restrict__ xe,
                                               const float* __restrict__ W1,
                                               float* __restrict__ p1,
                                               int* __restrict__ bars) {
  if (blockIdx.x == 0 && blockIdx.y == 0 && threadIdx.x == 0) {
    bars[0] = 0; bars[1] = 0;  // visible to k_tail after kernel boundary
  }
  __shared__ float red[11 * 32 * 36];  // 50688 B
  const int cg  = threadIdx.x & 7;
  const int ks  = threadIdx.x >> 3;
  const int col = blockIdx.x * 32 + cg * 4;
  const int k0  = blockIdx.y * 256 + ks * 8;

  float4 w[8];
#pragma unroll
  for (int i = 0; i < 8; ++i)
    w[i] = *(const float4*)&W1[(size_t)(k0 + i) * 512 + col];

  float4 acc[11];
#pragma unroll
  for (int r = 0; r < 11; ++r) acc[r] = make_float4(0.f, 0.f, 0.f, 0.f);

  {
    const float4 a = *(const float4*)&xn[k0];
    const float4 b = *(const float4*)&xn[k0 + 4];
    fma8(w, a, b, acc[0]);
  }
#pragma unroll
  for (int r = 0; r < 10; ++r) {
    const float4 a = *(const float4*)&xe[r * 8192 + k0];
    const float4 b = *(const float4*)&xe[r * 8192 + k0 + 4];
    fma8(w, a, b, acc[r + 1]);
  }

#pragma unroll
  for (int r = 0; r < 11; ++r)
    *(float4*)&red[(r * 32 + ks) * 36 + cg * 4] = acc[r];
  __syncthreads();

  for (int o = threadIdx.x; o < 352; o += 256) {
    const int r = o >> 5, c = o & 31;
    float s = 0.f;
#pragma unroll
    for (int k = 0; k < 32; ++k) s += red[(r * 32 + k) * 36 + c];
    p1[((size_t)blockIdx.y * 11 + r) * 512 + blockIdx.x * 32 + c] = s;
  }
}

// ---------------- Tail: 16 blocks x 1024, two-level last-man -----------------
// Phase A (block j): H1 cols [32j,32j+32) from p1 (no redundancy, 45 KB) with
// W2 k-slice pre-issued to regs (32 KB, overlapped) -> p2[j].
// Stage 2 (last 4 tickets, q): enc k-quarter [64q,64q+64): W3 regs issued
// BEFORE the straggler spin; p2 L3-warm -> encp[q].
// Stage 3 (last of 4): Wi1/Wi2 staged by ALL 1024 threads; similarity+MLP.
__global__ __launch_bounds__(1024) void k_tail(
    const float* __restrict__ p1, const float* __restrict__ b1,
    const float* __restrict__ W2, const float* __restrict__ b2,
    const float* __restrict__ W3, const float* __restrict__ b3,
    const float* __restrict__ mm,
    const float* __restrict__ Wi1, const float* __restrict__ bi1,
    const float* __restrict__ Wi2, const float* __restrict__ bi2,
    const float* __restrict__ Wi3, const float* __restrict__ bi3,
    float* __restrict__ p2, float* __restrict__ encp,
    int* __restrict__ bars, float* __restrict__ out) {
  __shared__ __align__(16) float smem[12368];  // 49.4 KB, re-carved per stage
  __shared__ int tick;
  const int t = threadIdx.x;
  const int j = blockIdx.x;

  // ---- Phase A: pre-issue W2 k-slice [32j,32j+32) into regs ----
  const int c = t & 255, kg = t >> 8;  // 256 cols x 4 k-groups of 8
  float w2r[8];
#pragma unroll
  for (int kk = 0; kk < 8; ++kk)
    w2r[kk] = W2[(size_t)(j * 32 + kg * 8 + kk) * 256 + c];

  // H1 cols [32j, 32j+32): 352 outputs, 32 unrolled coalesced p1 loads each.
  float* h1s = smem;  // 352
  if (t < 352) {
    const int r = t >> 5, cc = t & 31;
    const int col = j * 32 + cc;
    float s = b1[col];
#pragma unroll
    for (int ch = 0; ch < 32; ++ch) s += p1[(size_t)(ch * 11 + r) * 512 + col];
    h1s[r * 32 + cc] = fmaxf(s, 0.f);
  }
  __syncthreads();

  // H2 partial over this 32-k slice.
  float* redA = smem + 1024;  // [4][11][256]
  {
    float acc[11];
#pragma unroll
    for (int r = 0; r < 11; ++r) acc[r] = 0.f;
#pragma unroll
    for (int kk = 0; kk < 8; ++kk) {
      const int kl = kg * 8 + kk;
#pragma unroll
      for (int r = 0; r < 11; ++r)
        acc[r] = fmaf(h1s[r * 32 + kl], w2r[kk], acc[r]);
    }
#pragma unroll
    for (int r = 0; r < 11; ++r) redA[(kg * 11 + r) * 256 + c] = acc[r];
  }
  __syncthreads();
  for (int o = t; o < 2816; o += 1024) {
    const int r = o >> 8, cc = o & 255;
    p2[(size_t)j * 2816 + o] = redA[r * 256 + cc] + redA[(11 + r) * 256 + cc] +
                               redA[(22 + r) * 256 + cc] +
                               redA[(33 + r) * 256 + cc];
  }

  // ---- arrival 1: last 4 tickets become stage-2 workers ----
  __syncthreads();
  if (t == 0) {
    __threadfence();  // release our p2 slice
    tick = __hip_atomic_fetch_add(&bars[0], 1, __ATOMIC_ACQ_REL,
                                  __HIP_MEMORY_SCOPE_AGENT);
  }
  __syncthreads();
  const int rank = tick;
  if (rank < 12) return;
  const int q = rank - 12;  // 0..3

  // Pre-issue W3 k-quarter into regs BEFORE the spin (cold fetch overlaps it).
  const int c3 = t & 127, kg3 = t >> 7;  // 128 cols x 8 k-groups of 8
  float w3r[8];
#pragma unroll
  for (int kk = 0; kk < 8; ++kk)
    w3r[kk] = W3[(size_t)(q * 64 + kg3 * 8 + kk) * 128 + c3];

  if (t == 0) {  // wait for the last ~3 stragglers of 16 equal-work blocks
    while (__hip_atomic_load(&bars[0], __ATOMIC_RELAXED,
                             __HIP_MEMORY_SCOPE_AGENT) < 16)
      __builtin_amdgcn_s_sleep(1);
    __threadfence();  // acquire: all 16 p2 slices visible
  }
  __syncthreads();

  // ---- Stage 2: H2 k-quarter + enc partial ----
  float* h2q = smem;  // 704
  if (t < 704) {
    const int r = t >> 6, kk = t & 63;
    const int col = q * 64 + kk;
    float s = b2[col];
#pragma unroll
    for (int jj = 0; jj < 16; ++jj) s += p2[(size_t)jj * 2816 + r * 256 + col];
    h2q[r * 64 + kk] = fmaxf(s, 0.f);
  }
  __syncthreads();
  float* redB = smem + 1024;  // [8][11][128]
  {
    float acc[11];
#pragma unroll
    for (int r = 0; r < 11; ++r) acc[r] = 0.f;
#pragma unroll
    for (int kk = 0; kk < 8; ++kk) {
      const int kl = kg3 * 8 + kk;
#pragma unroll
      for (int r = 0; r < 11; ++r)
        acc[r] = fmaf(h2q[r * 64 + kl], w3r[kk], acc[r]);
    }
#pragma unroll
    for (int r = 0; r < 11; ++r) redB[(kg3 * 11 + r) * 128 + c3] = acc[r];
  }
  __syncthreads();
  for (int o = t; o < 1408; o += 1024) {
    const int r = o >> 7, cc = o & 127;
    float s = 0.f;
#pragma unroll
    for (int g = 0; g < 8; ++g) s += redB[(g * 11 + r) * 128 + cc];
    encp[(size_t)q * 1408 + o] = s;
  }

  // ---- arrival 2: last of the 4 runs the finale (no spin needed) ----
  __syncthreads();
  if (t == 0) {
    __threadfence();
    tick = __hip_atomic_fetch_add(&bars[1], 1, __ATOMIC_ACQ_REL,
                                  __HIP_MEMORY_SCOPE_AGENT);
  }
  __syncthreads();
  if (tick != 3) return;
  if (t == 0) __threadfence();  // acquire: all 4 encp slices visible
  __syncthreads();

  // ---- Stage 3: stage Wi1/Wi2 with ALL threads; enc; similarity; MLP ----
  float* encs = smem;           // 1408
  float* wi1s = smem + 1536;    // 8576  (offset 6144 B, 16B-aligned)
  float* wi2s = smem + 10112;   // 2048
  float* comb = smem + 12160;   // 134
  float* h1b  = smem + 12296;   // 64
  for (int i = t; i < 2144; i += 1024)
    ((f32x4*)wi1s)[i] = ((const f32x4*)Wi1)[i];
  if (t < 512) ((f32x4*)wi2s)[t] = ((const f32x4*)Wi2)[t];
  for (int o = t; o < 1408; o += 1024) {
    float s = b3[o & 127];
#pragma unroll
    for (int g = 0; g < 4; ++g) s += encp[(size_t)g * 1408 + o];
    encs[o] = s;  // encoder outputs incl. bias; row 0 = new_knowledge
  }
  __syncthreads();

  float consist = 0.f;
  float n0 = 0.f, n1 = 0.f;
  if (t < 64) {
    n0 = encs[t]; n1 = encs[64 + t];
    comb[t] = n0; comb[64 + t] = n1;
    if (t < 6) comb[128 + t] = mm[t];
  }
  __syncthreads();  // comb ready
  if (t < 64) {
    // wave 0: similarity (concurrent with wave 1's MLP layer 1)
    const float nn = wredsum(n0 * n0 + n1 * n1);
#pragma unroll
    for (int r = 1; r <= 10; ++r) {
      const float e0 = encs[r * 128 + t];
      const float e1 = encs[r * 128 + 64 + t];
      const float d0 = e0 - n0, d1 = e1 - n1;
      const float g  = wredsum(d0 * d0 + d1 * d1);
      const float qq = wredsum(e0 * e0 + e1 * e1);
      const float dd = wredsum(e0 * n0 + e1 * n1);
      if (t == 0) {
        const float geo = sqrtf(g);
        const float den = fmaxf(sqrtf(nn), EPS) * fmaxf(sqrtf(qq), EPS);
        consist += geo - dd / den;
      }
    }
  } else if (t < 128) {
    // wave 1: integrator layer 1 (Wi1 from LDS)
    const int tt = t - 64;
    float h = bi1[tt];
#pragma unroll 4
    for (int k = 0; k < 134; ++k) h = fmaf(comb[k], wi1s[k * 64 + tt], h);
    h1b[tt] = fmaxf(h, 0.f);
  }
  __syncthreads();
  if (t < 64) {
    float part = 0.f;
    if (t < 32) {
      float hh = bi2[t];
#pragma unroll 8
      for (int k = 0; k < 64; ++k) hh = fmaf(h1b[k], wi2s[k * 32 + t], hh);
      part = fmaxf(hh, 0.f) * Wi3[t];
    }
    const float qual = wredsum(part);
    if (t == 0) out[0] = consist * 0.1f + expf(-(qual + bi3[0]));
  }
}

extern "C" void kernel_launch(void* const* d_in, const int* in_sizes, int n_in,
                              void* d_out, int out_size, void* d_ws, size_t ws_size,
                              hipStream_t stream) {
  (void)in_sizes; (void)n_in; (void)out_size; (void)ws_size;
  const float* xn  = (const float*)d_in[0];
  const float* xe  = (const float*)d_in[1];
  const float* mm  = (const float*)d_in[2];
  const float* W1  = (const float*)d_in[3];
  const float* b1  = (const float*)d_in[4];
  const float* W2  = (const float*)d_in[5];
  const float* b2  = (const float*)d_in[6];
  const float* W3  = (const float*)d_in[7];
  const float* b3  = (const float*)d_in[8];
  const float* Wi1 = (const float*)d_in[9];
  const float* bi1 = (const float*)d_in[10];
  const float* Wi2 = (const float*)d_in[11];
  const float* bi2 = (const float*)d_in[12];
  const float* Wi3 = (const float*)d_in[13];
  const float* bi3 = (const float*)d_in[14];
  float* out = (float*)d_out;

  char* ws = (char*)d_ws;
  float* p1   = (float*)(ws);            // 32*11*512*4 = 720896 B
  float* p2   = (float*)(ws + 720896);   // 16*11*256*4 = 180224 B
  float* encp = (float*)(ws + 901120);   // 4*11*128*4  =  22528 B
  int*   bars = (int*)  (ws + 923648);   // 8 B

  hipLaunchKernelGGL(k_l1,   dim3(16, 32), dim3(256),  0, stream, xn, xe, W1, p1, bars);
  hipLaunchKernelGGL(k_tail, dim3(16),     dim3(1024), 0, stream,
                     p1, b1, W2, b2, W3, b3, mm,
                     Wi1, bi1, Wi2, bi2, Wi3, bi3, p2, encp, bars, out);
}